// Round 3
// baseline (546.212 us; speedup 1.0000x reference)
//
#include <hip/hip_runtime.h>
#include <hip/hip_bf16.h>

// B=8, H=W=128, C=F=256, 3x3 modulated conv (StyleGAN2 style).
// bf16 MFMA implicit GEMM. Block = 128 rows x 256 F, 4 waves of 64x128.
// Round-3 structure: A staged in LDS (double-buffered, 1 barrier/chunk);
// B loaded DIRECTLY global->VGPR (per-lane contiguous 16B; wm is XCD-L2-resident),
// register-double-buffered one tap ahead (counted-vmcnt pipeline, no LDS round trip).

#define NB 8
#define NH 128
#define NW 128
#define NC 256
#define NF 256

typedef __attribute__((ext_vector_type(8))) short bf16x8;
typedef __attribute__((ext_vector_type(4))) float f32x4;

// async 16B global -> LDS (dest = wave-uniform base + lane*16)
__device__ __forceinline__ void gload16(const ushort* g, ushort* l) {
    __builtin_amdgcn_global_load_lds(
        (const __attribute__((address_space(1))) unsigned int*)g,
        (__attribute__((address_space(3))) unsigned int*)l, 16, 0, 0);
}

// ---------------- x fp32 -> bf16 ----------------
__global__ void k_cvt(const float* __restrict__ x, ushort* __restrict__ xbf) {
    int i = (blockIdx.x * blockDim.x + threadIdx.x) * 4;
    float4 v = *(const float4*)(x + i);
    union { ushort4 u; __hip_bfloat16 h[4]; } o;
    o.h[0] = __float2bfloat16(v.x);
    o.h[1] = __float2bfloat16(v.y);
    o.h[2] = __float2bfloat16(v.z);
    o.h[3] = __float2bfloat16(v.w);
    *(ushort4*)(xbf + i) = o.u;
}

// ---------------- modulate + demodulate weights ----------------
__global__ void k_modw(const float* __restrict__ kern, const float* __restrict__ style,
                       ushort* __restrict__ wm) {
    int b = blockIdx.x >> 8;
    int f = blockIdx.x & 255;
    int c = threadIdx.x;
    float s = style[b * 256 + c] + 1.0f;
    float w[9];
    float acc = 0.f;
#pragma unroll
    for (int t = 0; t < 9; ++t) {
        w[t] = kern[(t * 256 + c) * 256 + f] * s;
        acc += w[t] * w[t];
    }
#pragma unroll
    for (int off = 32; off; off >>= 1) acc += __shfl_down(acc, off);
    __shared__ float part[4];
    if ((threadIdx.x & 63) == 0) part[threadIdx.x >> 6] = acc;
    __syncthreads();
    float total = part[0] + part[1] + part[2] + part[3];
    float inv = 1.0f / sqrtf(total + 1e-8f);
#pragma unroll
    for (int t = 0; t < 9; ++t) {
        union { ushort u; __hip_bfloat16 h; } o;
        o.h = __float2bfloat16(w[t] * inv);
        wm[(((b * 9 + t) * 256 + f) * 256) + c] = o.u;
    }
}

// ---------------- conv as implicit GEMM ----------------
// Grid = B*H = 1024 blocks, XCD-swizzled (one sample b per XCD).
// K loop: 8 chunks of 32 c x 9 taps. Per tap per wave: 8 global B-frag loads
// (NEXT tap, reg-dbuf) + 4 LDS A-frag reads (this tap) + 32 MFMA. 1 barrier/chunk.
__global__ void __launch_bounds__(256, 2)
k_conv(const ushort* __restrict__ xbf, const ushort* __restrict__ wm,
       float* __restrict__ out) {
    const int bidx = (blockIdx.x & 7) * 128 + (blockIdx.x >> 3);
    const int h = bidx & 127;
    const int b = bidx >> 7;

    __shared__ ushort As[2][3][130 * 32];   // [buf][dh][(w+1)*32 + c], w in [-1,128]

    const int tid = threadIdx.x;
    const int wave = tid >> 6, lane = tid & 63;
    const int wm_ = wave & 1, wn_ = wave >> 1;   // wave tile: rows wm_*64, cols wn_*128
    const int lrow = lane & 15;
    const int quad = lane >> 4;
    const int lw = lane >> 2;          // staging: 16 rows per wave-load
    const int lc = (lane & 3) * 8;     // 4 x 16B per row

    // Zero halo columns (w=-1 and w=128) in both buffers, constant across chunks.
#pragma unroll
    for (int p = 0; p < 2; ++p) {
        if (tid < 3 * 2 * 32) {
            int dh = tid >> 6;
            int side = (tid >> 5) & 1;
            int cc = tid & 31;
            As[p][dh][(side ? 129 : 0) * 32 + cc] = 0;
        }
    }
    // Zero out-of-image rows once in both buffers (stageA always skips them).
#pragma unroll
    for (int dh = 0; dh < 3; ++dh) {
        int hp = h + dh - 1;
        if (hp < 0 || hp >= 128) {
            for (int i = tid; i < 130 * 32; i += 256) {
                As[0][dh][i] = 0;
                As[1][dh][i] = 0;
            }
        }
    }

    f32x4 acc[4][8];
    const f32x4 zero4 = {0.f, 0.f, 0.f, 0.f};
#pragma unroll
    for (int mi = 0; mi < 4; ++mi)
#pragma unroll
        for (int ni = 0; ni < 8; ++ni) acc[mi][ni] = zero4;

    const ushort* wmb = wm + (size_t)b * 9 * 65536;
    // per-lane B base: row (F) = wn_*128 + lrow, col base quad*8
    const ushort* wrow = wmb + (wn_ * 128 + lrow) * 256 + quad * 8;

    auto stageA = [&](int c0, int p) {
#pragma unroll
        for (int dh = 0; dh < 3; ++dh) {
            int hp = h + dh - 1;
            if (hp >= 0 && hp < 128) {
                const ushort* src = xbf + ((size_t)(b * 128 + hp) * 128) * 256 + c0;
#pragma unroll
                for (int j = 0; j < 2; ++j) {
                    int w = j * 64 + wave * 16;      // wave-uniform base row
                    gload16(src + (w + lw) * 256 + lc, &As[p][dh][(w + 1) * 32]);
                }
            }
        }
    };

    bf16x8 af[4];
    bf16x8 bfr[2][8];   // reg double-buffer: tap with parity q uses bfr[q]

    // prologue: chunk0 A in flight; tap0 B into bfr[0]
    stageA(0, 0);
#pragma unroll
    for (int ni = 0; ni < 8; ++ni)
        bfr[0][ni] = *(const bf16x8*)(wrow + ni * 4096);

    // chunks processed in pairs so tap parity stays compile-time static
    for (int ci2 = 0; ci2 < 4; ++ci2) {
#pragma unroll
        for (int half = 0; half < 2; ++half) {
            const int ci = 2 * ci2 + half;
            const int c0 = ci * 32;
            __syncthreads();          // As[half] staged; readers of As[half^1] done
            if (ci < 7) stageA(c0 + 32, half ^ 1);
#pragma unroll
            for (int t = 0; t < 9; ++t) {
                const int par = (half + t) & 1;          // static
                // issue NEXT tap's B loads (reg-dbuf; flies under this tap's MFMAs)
                if (t < 8) {
                    const ushort* src = wrow + (t + 1) * 65536 + c0;
#pragma unroll
                    for (int ni = 0; ni < 8; ++ni)
                        bfr[par ^ 1][ni] = *(const bf16x8*)(src + ni * 4096);
                } else if (ci < 7) {
                    const ushort* src = wrow + (c0 + 32);  // tap0, next chunk
#pragma unroll
                    for (int ni = 0; ni < 8; ++ni)
                        bfr[par ^ 1][ni] = *(const bf16x8*)(src + ni * 4096);
                }
                const int dh = t / 3, dw = t % 3;
#pragma unroll
                for (int mi = 0; mi < 4; ++mi) {
                    int w = wm_ * 64 + mi * 16 + lrow;
                    af[mi] = *(const bf16x8*)&As[half][dh][(w + dw) * 32 + quad * 8];
                }
#pragma unroll
                for (int mi = 0; mi < 4; ++mi)
#pragma unroll
                    for (int ni = 0; ni < 8; ++ni)
                        acc[mi][ni] = __builtin_amdgcn_mfma_f32_16x16x32_bf16(
                            af[mi], bfr[par][ni], acc[mi][ni], 0, 0, 0);
            }
        }
    }

    // ---- epilogue: C/D layout col=lane&15, row=quad*4+reg ----
    float* obase = out + ((size_t)(b * 128 + h) * 128) * 256;
#pragma unroll
    for (int mi = 0; mi < 4; ++mi) {
        int wrow_ = wm_ * 64 + mi * 16 + quad * 4;
#pragma unroll
        for (int ni = 0; ni < 8; ++ni) {
            int f = wn_ * 128 + ni * 16 + lrow;
            f32x4 v = acc[mi][ni];
#pragma unroll
            for (int r = 0; r < 4; ++r) {
                obase[(wrow_ + r) * 256 + f] = v[r];
            }
        }
    }
}

extern "C" void kernel_launch(void* const* d_in, const int* in_sizes, int n_in,
                              void* d_out, int out_size, void* d_ws, size_t ws_size,
                              hipStream_t stream) {
    const float* x     = (const float*)d_in[0];   // [8,128,128,256]
    const float* style = (const float*)d_in[1];   // [8,1,1,256]
    const float* kern  = (const float*)d_in[2];   // [3,3,256,256]
    float* out = (float*)d_out;                   // [8,128,128,256]

    ushort* xbf = (ushort*)d_ws;                  // 64 MiB
    ushort* wmod = xbf + (size_t)NB * NH * NW * NC;  // 9 MiB

    k_cvt<<<(NB * NH * NW * NC) / (256 * 4), 256, 0, stream>>>(x, xbf);
    k_modw<<<NB * NF, 256, 0, stream>>>(kern, style, wmod);
    k_conv<<<NB * NH, 256, 0, stream>>>(xbf, wmod, out);
}